// Round 10
// baseline (14046.854 us; speedup 1.0000x reference)
//
#include <hip/hip_runtime.h>
#include <hip/hip_cooperative_groups.h>

namespace cg = cooperative_groups;

typedef __bf16 bf16x8 __attribute__((ext_vector_type(8)));
typedef __bf16 bf16x4 __attribute__((ext_vector_type(4)));
typedef __bf16 bf16x2 __attribute__((ext_vector_type(2)));
typedef float  f32x4  __attribute__((ext_vector_type(4)));

__device__ __forceinline__ void gl_lds16(const void* g, void* l) {
  __builtin_amdgcn_global_load_lds((const __attribute__((address_space(1))) void*)g,
                                   (__attribute__((address_space(3))) void*)l, 16, 0, 0);
}

// ---------------- prep / elementwise kernels ----------------

__global__ void k_diag(float* __restrict__ out, int n, float v) {
  int i = blockIdx.x * 256 + threadIdx.x;
  if (i < n) out[i] = v;
}

__global__ void k_cast(const float* __restrict__ s, __bf16* __restrict__ d, int n) {
  int i = (blockIdx.x * 256 + threadIdx.x) * 4;
  if (i >= n) return;
  float4 v = *(const float4*)(s + i);
  bf16x4 o = { (__bf16)v.x, (__bf16)v.y, (__bf16)v.z, (__bf16)v.w };
  *(bf16x4*)(d + i) = o;
}

// strided cast: d[r*ldo + coff + c] = bf16(s[r*2^cshift + c])
__global__ void k_cast2(const float* __restrict__ s, __bf16* __restrict__ d,
                        int cshift, int ldo, int coff, int n) {
  int i = (blockIdx.x * 256 + threadIdx.x) * 4;
  if (i >= n) return;
  int r = i >> cshift, c = i & ((1 << cshift) - 1);
  float4 v = *(const float4*)(s + i);
  bf16x4 o = { (__bf16)v.x, (__bf16)v.y, (__bf16)v.z, (__bf16)v.w };
  *(bf16x4*)(d + (size_t)r * ldo + coff + c) = o;
}

__global__ void k_casttag(const float* __restrict__ s, __bf16* __restrict__ d) {
  int i = (blockIdx.x * 256 + threadIdx.x) * 4;  // over 128*1024
  if (i >= 128 * 1024) return;
  int r = i >> 10;
  bf16x4 o;
  if (r < 106) {
    float4 v = *(const float4*)(s + i);
    o = (bf16x4){ (__bf16)v.x, (__bf16)v.y, (__bf16)v.z, (__bf16)v.w };
  } else {
    o = (bf16x4){ (__bf16)0.f, (__bf16)0.f, (__bf16)0.f, (__bf16)0.f };
  }
  *(bf16x4*)(d + i) = o;
}

__global__ void k_padvec(const float* __restrict__ s, float* __restrict__ d) {
  int i = threadIdx.x;  // 128
  d[i] = (i < 106) ? s[i] : 0.0f;
}

__global__ void k_embed(const int* __restrict__ sent, const float* __restrict__ emb,
                        __bf16* __restrict__ x) {
  int row = blockIdx.x;            // t*64 + b
  int t = row >> 6, b = row & 63;
  int idx = sent[b * 256 + t];
  const float2* src = (const float2*)(emb + (size_t)idx * 512);
  float2 v = src[threadIdx.x];
  bf16x2 o = { (__bf16)v.x, (__bf16)v.y };
  *(bf16x2*)(x + (size_t)row * 512 + threadIdx.x * 2) = o;
}

__global__ void k_softmax(const float* __restrict__ lg, float* __restrict__ out) {
  int row = blockIdx.x;            // t*64+b
  int t = row >> 6, b = row & 63;
  int l = threadIdx.x;             // 64
  const float* lr = lg + (size_t)row * 128;
  float v0 = (l < 106)      ? lr[l]      : -1e30f;
  float v1 = (l + 64 < 106) ? lr[l + 64] : -1e30f;
  float m = fmaxf(v0, v1);
  #pragma unroll
  for (int s = 32; s; s >>= 1) m = fmaxf(m, __shfl_xor(m, s));
  float e0 = (l < 106)      ? __expf(v0 - m) : 0.f;
  float e1 = (l + 64 < 106) ? __expf(v1 - m) : 0.f;
  float sum = e0 + e1;
  #pragma unroll
  for (int s = 32; s; s >>= 1) sum += __shfl_xor(sum, s);
  float inv = 1.f / sum;
  float* o = out + ((size_t)b * 256 + t) * 106;
  if (l < 106) o[l] = e0 * inv;
  if (l + 64 < 106) o[l + 64] = e1 * inv;
}

// ---------------- generic MFMA GEMM: C[M,N] = A[M,K] @ W[N,K]^T (+bias, +tanh) ----------------

template<typename OutT, int HASB, int ACT>
__global__ __launch_bounds__(256, 2) void k_gemm(
    const __bf16* __restrict__ A, int lda,
    const __bf16* __restrict__ W, int ldw,
    OutT* __restrict__ C, int ldc,
    const float* __restrict__ bias, int K)
{
  __shared__ __bf16 As[128 * 32];
  __shared__ __bf16 Ws[128 * 32];
  const int tid = threadIdx.x;
  const int wave = tid >> 6, lane = tid & 63;
  const int wr = wave >> 1, wc = wave & 1;
  const int ln = lane & 15, kh = lane >> 4;
  const long brow = (long)blockIdx.y * 128;
  const long bcol = (long)blockIdx.x * 128;
  f32x4 acc[4][4] = {};
  const int rsub = lane >> 2;         // 0..15
  const int ksub = (lane & 3) * 8;    // element offset in k
  for (int kt = 0; kt < (K >> 5); ++kt) {
    #pragma unroll
    for (int ii = 0; ii < 2; ++ii) {
      int inst = wave * 2 + ii;
      const __bf16* ga = A + (brow + inst * 16 + rsub) * (long)lda + kt * 32 + ksub;
      gl_lds16(ga, (char*)As + inst * 1024);
      const __bf16* gw = W + (bcol + inst * 16 + rsub) * (long)ldw + kt * 32 + ksub;
      gl_lds16(gw, (char*)Ws + inst * 1024);
    }
    __syncthreads();
    bf16x8 af[4], wf[4];
    #pragma unroll
    for (int i = 0; i < 4; ++i)
      af[i] = *(const bf16x8*)(As + (wr * 64 + i * 16 + ln) * 32 + kh * 8);
    #pragma unroll
    for (int j = 0; j < 4; ++j)
      wf[j] = *(const bf16x8*)(Ws + (wc * 64 + j * 16 + ln) * 32 + kh * 8);
    #pragma unroll
    for (int i = 0; i < 4; ++i)
      #pragma unroll
      for (int j = 0; j < 4; ++j)
        acc[i][j] = __builtin_amdgcn_mfma_f32_16x16x32_bf16(af[i], wf[j], acc[i][j], 0, 0, 0);
    __syncthreads();
  }
  #pragma unroll
  for (int j = 0; j < 4; ++j) {
    long col = bcol + wc * 64 + j * 16 + ln;
    float bv = HASB ? bias[col] : 0.f;
    #pragma unroll
    for (int i = 0; i < 4; ++i) {
      long row0 = brow + wr * 64 + i * 16 + kh * 4;
      #pragma unroll
      for (int r = 0; r < 4; ++r) {
        float v = acc[i][j][r] + bv;
        if (ACT) v = tanhf(v);
        C[(row0 + r) * (long)ldc + col] = (OutT)v;
      }
    }
  }
}

// ---------------- persistent recurrent kernel (cooperative, augmented-K) ----------------
// Gates G[64, 4*SD] = [S_{t-1} | in_chunks(t)] @ Waug^T + b.  Waug [4*SD, K], K = SD + NIN*512.
// Each block owns UN = COLS/4 hidden units (COLS gate-cols). Waug slice LDS-resident, XOR-swizzled.
// NIN==1 (LSTMP): chunk = X[xr], xr = dir ? 255-t : t, mask time xr. DIRS=2 packs both dirs.
// NIN==2 (LSTMO): chunk0 = HPF[t], chunk1 = HPB[255-t], mask time t.
// Grid sync via cooperative groups (launched with hipLaunchCooperativeKernel).

template<int SD, int NIN, int COLS, int DIRS>
__global__ __launch_bounds__(256, 1) void k_rnn(
    const __bf16* __restrict__ W0, const __bf16* __restrict__ W1,
    const __bf16* __restrict__ inA0, const __bf16* __restrict__ inA1,
    const __bf16* __restrict__ inB,
    const float* __restrict__ b0, const float* __restrict__ b1,
    __bf16* __restrict__ S0, __bf16* __restrict__ S1,
    const int* __restrict__ lens)
{
  constexpr int K   = SD + NIN * 512;
  constexpr int UN  = COLS / 4;      // hidden units per block
  constexpr int CG  = COLS / 2;      // cols per wave-column-group
  constexpr int NJ  = CG / 16;       // 16-col fragments per wave
  constexpr int NBD = (4 * SD) / COLS;
  constexpr int NRT = UN / 4;        // batch rows per thread in epilogue
  extern __shared__ char smem[];
  float* gbuf = (float*)(smem + (size_t)COLS * K * 2);
  cg::grid_group gg = cg::this_grid();

  const int bid  = blockIdx.x;
  const int dir  = (DIRS == 2 && bid >= NBD) ? 1 : 0;
  const int bidl = bid - dir * NBD;
  const __bf16* Wp  = dir ? W1 : W0;
  const __bf16* inA = dir ? inA1 : inA0;
  const float*  bp  = dir ? b1 : b0;
  __bf16* Sp = dir ? S1 : S0;

  const int tid = threadIdx.x;
  const int lane = tid & 63, wave = tid >> 6;
  const int wr = wave >> 1, wc = wave & 1;
  const int ln = lane & 15, kh = lane >> 4;

  // one-time: Waug slice (COLS rows x K) -> LDS, XOR-swizzled
  {
    constexpr int TPC = 256 / COLS;
    constexpr int KPQ = K / TPC;
    int c = tid / TPC, q = tid % TPC;
    int gate = c / UN, uu = c % UN;
    const __bf16* wsrc = Wp + ((size_t)(gate * SD + bidl * UN + uu)) * K + q * KPQ;
    for (int k8 = 0; k8 < KPQ; k8 += 8) {
      bf16x8 v = *(const bf16x8*)(wsrc + k8);
      int kk = q * KPQ + k8;
      int byte = ((c * K + kk) * 2) ^ ((c & 7) << 4);
      *(bf16x8*)(smem + byte) = v;
    }
  }
  const int u = tid % UN, rg = tid / UN;
  float bz[4];
  #pragma unroll
  for (int g = 0; g < 4; ++g) bz[g] = bp[g * SD + bidl * UN + u];
  int len_r[NRT]; float cst[NRT], hst[NRT];
  #pragma unroll
  for (int e = 0; e < NRT; ++e) { len_r[e] = lens[rg * NRT + e]; cst[e] = 0.f; hst[e] = 0.f; }
  __syncthreads();

  for (int t = 0; t < 256; ++t) {
    if (t > 0) gg.sync();
    f32x4 acc[2][NJ] = {};
    int tA, tB, mT;
    if (NIN == 1) { tA = dir ? 255 - t : t; tB = 0; mT = tA; }
    else          { tA = t; tB = 255 - t; mT = t; }

    auto seg = [&](const __bf16* base, int ld, int kbase, int nks) {
      const __bf16* rp0 = base + (size_t)(32 * wr + ln) * ld + kh * 8;
      const __bf16* rp1 = base + (size_t)(32 * wr + 16 + ln) * ld + kh * 8;
      #pragma unroll 4
      for (int ks = 0; ks < nks; ++ks) {
        bf16x8 af[2], wf[NJ];
        af[0] = *(const bf16x8*)(rp0 + ks * 32);
        af[1] = *(const bf16x8*)(rp1 + ks * 32);
        #pragma unroll
        for (int j = 0; j < NJ; ++j) {
          int cl = wc * CG + j * 16 + ln;
          int kk = kbase + ks * 32 + kh * 8;
          wf[j] = *(const bf16x8*)(smem + (((cl * K + kk) * 2) ^ ((cl & 7) << 4)));
        }
        #pragma unroll
        for (int i = 0; i < 2; ++i)
          #pragma unroll
          for (int j = 0; j < NJ; ++j)
            acc[i][j] = __builtin_amdgcn_mfma_f32_16x16x32_bf16(af[i], wf[j], acc[i][j], 0, 0, 0);
      }
    };
    if (t > 0) seg(Sp + (size_t)(t - 1) * 64 * SD, SD, 0, SD / 32);
    seg(inA + (size_t)tA * 64 * 512, 512, SD, 16);
    if (NIN == 2) seg(inB + (size_t)tB * 64 * 512, 512, SD + 512, 16);

    #pragma unroll
    for (int i = 0; i < 2; ++i)
      #pragma unroll
      for (int j = 0; j < NJ; ++j)
        #pragma unroll
        for (int r = 0; r < 4; ++r)
          gbuf[(32 * wr + 16 * i + kh * 4 + r) * (COLS + 1) + (wc * CG + j * 16 + ln)] = acc[i][j][r];
    __syncthreads();

    #pragma unroll
    for (int e = 0; e < NRT; ++e) {
      int r = rg * NRT + e;
      const float* gr = gbuf + r * (COLS + 1);
      float gi = gr[0 * UN + u] + bz[0];
      float gf = gr[1 * UN + u] + bz[1];
      float gg2 = gr[2 * UN + u] + bz[2];
      float go = gr[3 * UN + u] + bz[3];
      float si = 1.f / (1.f + __expf(-gi));
      float sf = 1.f / (1.f + __expf(-gf));
      float so = 1.f / (1.f + __expf(-go));
      float cn = sf * cst[e] + si * tanhf(gg2);
      float hn = so * tanhf(cn);
      if (mT < len_r[e]) { cst[e] = cn; hst[e] = hn; }
      Sp[((size_t)t * 64 + r) * SD + bidl * UN + u] = (__bf16)hst[e];
    }
    __syncthreads();
  }
}

// ---------------- launch ----------------

extern "C" void kernel_launch(void* const* d_in, const int* in_sizes, int n_in,
                              void* d_out, int out_size, void* d_ws, size_t ws_size,
                              hipStream_t stream)
{
  const int*   sent  = (const int*)d_in[0];
  const int*   lens  = (const int*)d_in[1];
  const float* emb   = (const float*)d_in[2];
  const float* pwihf = (const float*)d_in[3];
  const float* pwhhf = (const float*)d_in[4];
  const float* pbf   = (const float*)d_in[5];
  const float* pwhrf = (const float*)d_in[6];
  const float* pwihb = (const float*)d_in[7];
  const float* pwhhb = (const float*)d_in[8];
  const float* pbb   = (const float*)d_in[9];
  const float* pwhrb = (const float*)d_in[10];
  const float* owih  = (const float*)d_in[11];
  const float* owhh  = (const float*)d_in[12];
  const float* ob    = (const float*)d_in[13];
  const float* owht  = (const float*)d_in[14];
  const float* obt   = (const float*)d_in[15];
  const float* tgw   = (const float*)d_in[16];
  const float* tgb   = (const float*)d_in[17];
  float* out = (float*)d_out;
  char* ws = (char*)d_ws;

  // --- workspace layout (bytes) ---
  const size_t O_XBF   = 0;            // 16 MB  [16384,512] bf16 ; LG aliases after LSTMP
  const size_t O_HPF   = 16777216;     // 16 MB  ; TN aliases HPF+HPB after LSTMO
  const size_t O_HPB   = 33554432;     // 16 MB
  const size_t O_HN    = 50331648;     // 32 MB  ; prep temps alias here before LSTMO
  const size_t O_WAUGF = 83886080;     // 4 MB   [2048,1024]
  const size_t O_WAUGB = 88080384;     // 4 MB
  const size_t O_WAUGO = 92274688;     // 16 MB  [4096,2048]
  const size_t O_WHT   = 109051904;    // 2 MB
  const size_t O_TAGW  = 111149056;    // 256 KB
  const size_t O_TAGB  = 111411200;    // 512 B
  const size_t NEED    = 111415808;
  if (ws_size < NEED) {   // diagnostic: encode ws_size into output
    k_diag<<<dim3((out_size + 255) / 256), dim3(256), 0, stream>>>(out, out_size, (float)ws_size);
    return;
  }

  __bf16 *XBF=(__bf16*)(ws+O_XBF), *HPF=(__bf16*)(ws+O_HPF), *HPB=(__bf16*)(ws+O_HPB),
    *HN=(__bf16*)(ws+O_HN), *TN=(__bf16*)(ws+O_HPF),
    *WAUGF=(__bf16*)(ws+O_WAUGF), *WAUGB=(__bf16*)(ws+O_WAUGB), *WAUGO=(__bf16*)(ws+O_WAUGO),
    *WHT=(__bf16*)(ws+O_WHT), *TAGW=(__bf16*)(ws+O_TAGW);
  // prep temps in HN region (dead before LSTMO writes HN)
  __bf16 *WHHF=(__bf16*)(ws+O_HN), *WHHB=(__bf16*)(ws+O_HN+2097152),
    *WHRF=(__bf16*)(ws+O_HN+4194304), *WHRB=(__bf16*)(ws+O_HN+4718592),
    *WIHOB=(__bf16*)(ws+O_HN+5242880);
  float* LG   = (float*)(ws+O_XBF);
  float* TAGB = (float*)(ws+O_TAGB);

  hipFuncSetAttribute((const void*)&k_rnn<512,1,64,2>,  hipFuncAttributeMaxDynamicSharedMemorySize, 147712);
  hipFuncSetAttribute((const void*)&k_rnn<1024,2,32,1>, hipFuncAttributeMaxDynamicSharedMemorySize, 139520);

  dim3 TB(256);
  auto cv = [&](const float* s, __bf16* d, int n){
    k_cast<<<dim3((n/4 + 255)/256), TB, 0, stream>>>(s, d, n);
  };
  // plain casts (temps + persistent)
  cv(pwhhf, WHHF, 2048*512);   cv(pwhhb, WHHB, 2048*512);
  cv(pwhrf, WHRF, 512*512);    cv(pwhrb, WHRB, 512*512);
  cv(owih,  WIHOB, 4096*1024); cv(owht,  WHT,  1024*1024);
  // strided casts into augmented weight right-halves
  k_cast2<<<dim3(1024), TB, 0, stream>>>(pwihf, WAUGF, 9, 1024, 512, 2048*512);
  k_cast2<<<dim3(1024), TB, 0, stream>>>(pwihb, WAUGB, 9, 1024, 512, 2048*512);
  k_cast2<<<dim3(4096), TB, 0, stream>>>(owhh,  WAUGO, 10, 2048, 0, 4096*1024);
  k_casttag<<<dim3(128), TB, 0, stream>>>(tgw, TAGW);
  k_padvec<<<dim3(1), dim3(128), 0, stream>>>(tgb, TAGB);
  k_embed<<<dim3(16384), TB, 0, stream>>>(sent, emb, XBF);

  // folded weights: Wc = Whh @ Whr^T (into WAUG left), WOIN = Wih_o[:,half] @ Whr^T (into WAUGO)
  k_gemm<__bf16,0,0><<<dim3(4,16), TB, 0, stream>>>(WHHF,512,      WHRF,512, WAUGF,1024,      (const float*)0, 512);
  k_gemm<__bf16,0,0><<<dim3(4,16), TB, 0, stream>>>(WHHB,512,      WHRB,512, WAUGB,1024,      (const float*)0, 512);
  k_gemm<__bf16,0,0><<<dim3(4,32), TB, 0, stream>>>(WIHOB,1024,    WHRF,512, WAUGO+1024,2048, (const float*)0, 512);
  k_gemm<__bf16,0,0><<<dim3(4,32), TB, 0, stream>>>(WIHOB+512,1024,WHRB,512, WAUGO+1536,2048, (const float*)0, 512);

  // bidirectional LSTMP (projection folded; input GEMM fused via augmented K=1024) — cooperative
  {
    const __bf16 *a0 = WAUGF, *a1 = WAUGB, *i0 = XBF, *i1 = XBF, *ib = nullptr;
    const float *bb0 = pbf, *bb1 = pbb;
    __bf16 *s0 = HPF, *s1 = HPB;
    const int* ll = lens;
    void* args[] = { &a0, &a1, &i0, &i1, &ib, &bb0, &bb1, &s0, &s1, &ll };
    hipLaunchCooperativeKernel((const void*)&k_rnn<512,1,64,2>, dim3(64), TB, args, 147712, stream);
  }

  // LSTMO (augmented K=2048: [h | hpf(t) | hpb(255-t)]) — cooperative
  {
    const __bf16 *a0 = WAUGO, *a1 = WAUGO, *i0 = HPF, *i1 = HPF, *ib = HPB;
    const float *bb0 = ob, *bb1 = ob;
    __bf16 *s0 = HN, *s1 = HN;
    const int* ll = lens;
    void* args[] = { &a0, &a1, &i0, &i1, &ib, &bb0, &bb1, &s0, &s1, &ll };
    hipLaunchCooperativeKernel((const void*)&k_rnn<1024,2,32,1>, dim3(128), TB, args, 139520, stream);
  }

  // deferred t-transform, tagger, softmax
  k_gemm<__bf16,1,1><<<dim3(8,128), TB, 0, stream>>>(HN,1024, WHT,1024, TN,1024, obt, 1024);
  k_gemm<float,1,0><<<dim3(1,128),  TB, 0, stream>>>(TN,1024, TAGW,1024, LG,128, TAGB, 1024);
  k_softmax<<<dim3(16384), dim3(64), 0, stream>>>(LG, out);
}